// Round 9
// baseline (250.051 us; speedup 1.0000x reference)
//
#include <hip/hip_runtime.h>
#include <cstdint>

// ---------------------------------------------------------------------------
// 2-layer GCN, zero scattered global atomics, per-node CSR gather.
// Both layers aggregate 64 B rows; the dense 16->32->16 MLP between the two
// aggregations runs as a separate register-resident kernel (de-fused from
// gather1 -- the fused LDS epilogue cost ~26 us of barrier/LDS overhead).
//
//  K1 hist:     per-chunk LDS histogram of bucket=col>>6 -> part[C][NB]
//  K2 colscan:  per-bucket scan over chunks -> base[C][NB], tot[NB]
//  scan1/2/3:   exclusive scan tot -> start[NB+1]
//  K4 place:    rw[pos] = {row | cl<<20, ew}  (bucket-sorted, normal stores)
//  K5 nodesort: per-bucket LDS count/scan -> ptr[node], dis=rsqrt(deg+1),
//               rw2 = node-sorted edge list {row, ew}
//  K6 xsc:      xsc = x * dis                                   [N,16]
//  K7 gather1:  wave/node: t = dis*(sum w*xsc[r] + xsc_self)    [N,16]
//  K8 mlp:      xs2 = (relu(t@W1^T + b1) @ W2^T) * dis          [N,16]
//  K9 gather2:  wave/node: out = dis*(sum w*xs2[r] + xs2_self)+b2
// ---------------------------------------------------------------------------

#define BS 64
#define CHUNKS 512

// nontemporal 8B edge-record load (int2 not accepted by the builtin)
__device__ __forceinline__ int2 nt_load_edge(const int2* p) {
    long long v = __builtin_nontemporal_load((const long long*)p);
    int2 r;
    r.x = (int)(v & 0xFFFFFFFFll);
    r.y = (int)(v >> 32);
    return r;
}

__global__ __launch_bounds__(1024) void hist_kernel(
        const int* __restrict__ col, int* __restrict__ part,
        int E, int nbuck, int per) {
    extern __shared__ int sh[];
    for (int t = threadIdx.x; t < nbuck; t += blockDim.x) sh[t] = 0;
    __syncthreads();
    int lo = blockIdx.x * per, hi = min(E, lo + per);
    for (int e = lo + threadIdx.x; e < hi; e += blockDim.x)
        atomicAdd(&sh[__builtin_nontemporal_load(&col[e]) >> 6], 1);
    __syncthreads();
    for (int t = threadIdx.x; t < nbuck; t += blockDim.x)
        part[(size_t)blockIdx.x * nbuck + t] = sh[t];
}

__global__ void colscan_kernel(const int* __restrict__ part, int* __restrict__ base,
                               int* __restrict__ tot, int nbuck) {
    int b = blockIdx.x;
    if (b >= nbuck) return;
    int lane = threadIdx.x;  // 64
    int off = 0;
    for (int g = 0; g < CHUNKS; g += 64) {
        int c = g + lane;
        int v = part[(size_t)c * nbuck + b];
        int s = v;
        #pragma unroll
        for (int d = 1; d < 64; d <<= 1) {
            int t = __shfl_up(s, d);
            if (lane >= d) s += t;
        }
        base[(size_t)c * nbuck + b] = off + (s - v);
        off += __shfl(s, 63);
    }
    if (lane == 0) tot[b] = off;
}

__global__ void scan1_kernel(const int* __restrict__ cnt, int* __restrict__ excl,
                             int* __restrict__ bsum, int n) {
    __shared__ int s[256];
    int tid = threadIdx.x;
    int i = blockIdx.x * 256 + tid;
    int v = (i < n) ? cnt[i] : 0;
    s[tid] = v;
    __syncthreads();
    for (int off = 1; off < 256; off <<= 1) {
        int t = (tid >= off) ? s[tid - off] : 0;
        __syncthreads();
        s[tid] += t;
        __syncthreads();
    }
    if (i < n) excl[i] = s[tid] - v;
    if (tid == 255) bsum[blockIdx.x] = s[255];
}

__global__ void scan2_kernel(int* __restrict__ bsum, int nb) {
    __shared__ int s[512];
    int tid = threadIdx.x;
    int v = (tid < nb) ? bsum[tid] : 0;
    s[tid] = v;
    __syncthreads();
    for (int off = 1; off < 512; off <<= 1) {
        int t = (tid >= off) ? s[tid - off] : 0;
        __syncthreads();
        s[tid] += t;
        __syncthreads();
    }
    if (tid < nb) bsum[tid] = s[tid] - v;
}

__global__ void scan3_kernel(int* __restrict__ excl, const int* __restrict__ bsum,
                             int n, int E) {
    int i = blockIdx.x * 256 + threadIdx.x;
    if (i < n) excl[i] += bsum[i >> 8];
    else if (i == n) excl[n] = E;
}

__global__ __launch_bounds__(1024) void place_kernel(
        const int* __restrict__ row, const int* __restrict__ col,
        const float* __restrict__ ew,
        const int* __restrict__ start, const int* __restrict__ base,
        int2* __restrict__ rw, int E, int nbuck, int per) {
    extern __shared__ int sh[];
    int* lbase = sh;
    int* cnt2  = sh + nbuck;
    int c = blockIdx.x;
    for (int t = threadIdx.x; t < nbuck; t += blockDim.x) {
        lbase[t] = start[t] + base[(size_t)c * nbuck + t];
        cnt2[t] = 0;
    }
    __syncthreads();
    int lo = c * per, hi = min(E, lo + per);
    for (int e = lo + threadIdx.x; e < hi; e += blockDim.x) {
        int cc = __builtin_nontemporal_load(&col[e]);
        int rr = __builtin_nontemporal_load(&row[e]);
        float w = __builtin_nontemporal_load(&ew[e]);
        int b = cc >> 6;
        int p = lbase[b] + atomicAdd(&cnt2[b], 1);
        int2 v;
        v.x = rr | ((cc & 63) << 20);
        v.y = __float_as_int(w);
        rw[p] = v;
    }
}

// per-bucket: per-node counts -> ptr, dis; node-sorted rw2 (row bits stripped)
__global__ __launch_bounds__(512) void nodesort_kernel(
        const int2* __restrict__ rw, const int* __restrict__ start,
        int2* __restrict__ rw2, int* __restrict__ ptr,
        float* __restrict__ dis, int N, int E, int nbuck) {
    __shared__ int cnt[BS];
    __shared__ float fdeg[BS];
    __shared__ int fill[BS];
    int b = blockIdx.x, tid = threadIdx.x;
    if (tid < BS) { cnt[tid] = 0; fdeg[tid] = 0.f; }
    __syncthreads();
    int s0 = start[b], s1 = start[b + 1];
    for (int e = s0 + tid; e < s1; e += 512) {
        int2 v = rw[e];
        int cl = v.x >> 20;
        atomicAdd(&cnt[cl], 1);
        atomicAdd(&fdeg[cl], __int_as_float(v.y));
    }
    __syncthreads();
    if (tid < BS) {
        int c = cnt[tid];
        int s = c;
        #pragma unroll
        for (int d = 1; d < BS; d <<= 1) {
            int t = __shfl_up(s, d);
            if (tid >= d) s += t;
        }
        int excl = s - c;
        ptr[b * BS + tid] = s0 + excl;
        fill[tid] = excl;
        int node = b * BS + tid;
        if (node < N) dis[node] = rsqrtf(fdeg[tid] + 1.0f);
    }
    __syncthreads();
    for (int e = s0 + tid; e < s1; e += 512) {
        int2 v = rw[e];
        int cl = v.x >> 20;
        int p = s0 + atomicAdd(&fill[cl], 1);
        int2 o;
        o.x = v.x & 0xFFFFF;
        o.y = v.y;
        rw2[p] = o;
    }
    if (b == 0 && tid == 0) ptr[nbuck * BS] = E;
}

// xsc = x * dis   (one float4 per thread)
__global__ void xsc_kernel(const float* __restrict__ x, const float* __restrict__ dis,
                           float* __restrict__ xsc, int N) {
    int gid = blockIdx.x * 256 + threadIdx.x;
    if (gid >= N * 4) return;
    int node = gid >> 2;
    float d = dis[node];
    float4 v = ((const float4*)x)[gid];
    v.x *= d; v.y *= d; v.z *= d; v.w *= d;
    ((float4*)xsc)[gid] = v;
}

// wave per node; lane = slot(16) x quad(4); 16 edges/iter, 64 B gathers.
// src: gather table [N,16]; writes dst = dis*(agg + src_self)   (pure gather)
__global__ __launch_bounds__(256) void gather1_kernel(
        const int* __restrict__ ptr, const int2* __restrict__ rw2,
        const float* __restrict__ src, const float* __restrict__ dis,
        float* __restrict__ dst, int N) {
    int node = (blockIdx.x * 256 + threadIdx.x) >> 6;
    int lane = threadIdx.x & 63;
    int slot = lane >> 2;          // 16 edge slots
    int q    = lane & 3;           // 4 float4 quads = 16 features
    if (node >= N) return;
    int s0 = ptr[node], s1 = ptr[node + 1];

    float4 a0 = {0.f, 0.f, 0.f, 0.f}, a1 = {0.f, 0.f, 0.f, 0.f};
    int e = s0 + slot;
    for (; e + 16 < s1; e += 32) {             // 2-way unroll, stride 16/slot
        int2 v0 = nt_load_edge(&rw2[e]);
        int2 v1 = nt_load_edge(&rw2[e + 16]);
        float4 x0 = *(const float4*)(src + (size_t)v0.x * 16 + q * 4);
        float4 x1 = *(const float4*)(src + (size_t)v1.x * 16 + q * 4);
        float w0 = __int_as_float(v0.y), w1 = __int_as_float(v1.y);
        a0.x += w0 * x0.x; a0.y += w0 * x0.y; a0.z += w0 * x0.z; a0.w += w0 * x0.w;
        a1.x += w1 * x1.x; a1.y += w1 * x1.y; a1.z += w1 * x1.z; a1.w += w1 * x1.w;
    }
    if (e < s1) {
        int2 v0 = nt_load_edge(&rw2[e]);
        float4 x0 = *(const float4*)(src + (size_t)v0.x * 16 + q * 4);
        float w0 = __int_as_float(v0.y);
        a0.x += w0 * x0.x; a0.y += w0 * x0.y; a0.z += w0 * x0.z; a0.w += w0 * x0.w;
    }
    a0.x += a1.x; a0.y += a1.y; a0.z += a1.z; a0.w += a1.w;
#pragma unroll
    for (int m = 4; m <= 32; m <<= 1) {        // reduce across 16 slots
        a0.x += __shfl_xor(a0.x, m);
        a0.y += __shfl_xor(a0.y, m);
        a0.z += __shfl_xor(a0.z, m);
        a0.w += __shfl_xor(a0.w, m);
    }

    if (slot == 0) {
        float d = dis[node];
        float4 self = *(const float4*)(src + (size_t)node * 16 + q * 4);
        float4 o;
        o.x = d * (a0.x + self.x);
        o.y = d * (a0.y + self.y);
        o.z = d * (a0.z + self.z);
        o.w = d * (a0.w + self.w);
        *(float4*)(dst + (size_t)node * 16 + q * 4) = o;
    }
}

// xs2 = (relu(t @ W1^T + b1) @ W2^T) * dis, thread per node, regs only.
// W1: [32,16] row-major, W2: [16,32] row-major. Weight reads are wave-uniform
// broadcasts from LDS (conflict-free).
__global__ __launch_bounds__(256) void mlp_kernel(
        const float* __restrict__ t, const float* __restrict__ dis,
        const float* __restrict__ W1, const float* __restrict__ b1,
        const float* __restrict__ W2, float* __restrict__ xs2, int N) {
    __shared__ float sW1[512];
    __shared__ float sW2[512];
    __shared__ float sb1[32];
    for (int k = threadIdx.x; k < 512; k += 256) {
        sW1[k] = W1[k];
        sW2[k] = W2[k];
    }
    if (threadIdx.x < 32) sb1[threadIdx.x] = b1[threadIdx.x];
    __syncthreads();
    int i = blockIdx.x * 256 + threadIdx.x;
    if (i >= N) return;

    float tr[16];
#pragma unroll
    for (int k = 0; k < 4; ++k) {
        float4 v = ((const float4*)(t + (size_t)i * 16))[k];
        tr[4*k+0] = v.x; tr[4*k+1] = v.y; tr[4*k+2] = v.z; tr[4*k+3] = v.w;
    }
    float h[32];
#pragma unroll
    for (int o = 0; o < 32; ++o) {
        float acc = sb1[o];
#pragma unroll
        for (int k = 0; k < 16; ++k) acc += tr[k] * sW1[o * 16 + k];
        h[o] = fmaxf(acc, 0.f);
    }
    float d = dis[i];
    float* outp = xs2 + (size_t)i * 16;
#pragma unroll
    for (int o = 0; o < 16; ++o) {
        float acc = 0.f;
#pragma unroll
        for (int k = 0; k < 32; ++k) acc += h[k] * sW2[o * 32 + k];
        outp[o] = acc * d;
    }
}

// wave per node; same gather shape; final epilogue adds b2.
__global__ __launch_bounds__(256) void gather2_kernel(
        const int* __restrict__ ptr, const int2* __restrict__ rw2,
        const float* __restrict__ xs2, const float* __restrict__ dis,
        const float* __restrict__ b2, float* __restrict__ out, int N) {
    int node = (blockIdx.x * 256 + threadIdx.x) >> 6;
    int lane = threadIdx.x & 63;
    int slot = lane >> 2;          // 16 edge slots
    int q    = lane & 3;           // 4 float4 quads = 16 features
    if (node >= N) return;
    int s0 = ptr[node], s1 = ptr[node + 1];

    float4 a0 = {0.f, 0.f, 0.f, 0.f}, a1 = {0.f, 0.f, 0.f, 0.f};
    int e = s0 + slot;
    for (; e + 16 < s1; e += 32) {             // 2-way unroll, stride 16/slot
        int2 v0 = nt_load_edge(&rw2[e]);
        int2 v1 = nt_load_edge(&rw2[e + 16]);
        float4 x0 = *(const float4*)(xs2 + (size_t)v0.x * 16 + q * 4);
        float4 x1 = *(const float4*)(xs2 + (size_t)v1.x * 16 + q * 4);
        float w0 = __int_as_float(v0.y), w1 = __int_as_float(v1.y);
        a0.x += w0 * x0.x; a0.y += w0 * x0.y; a0.z += w0 * x0.z; a0.w += w0 * x0.w;
        a1.x += w1 * x1.x; a1.y += w1 * x1.y; a1.z += w1 * x1.z; a1.w += w1 * x1.w;
    }
    if (e < s1) {
        int2 v0 = nt_load_edge(&rw2[e]);
        float4 x0 = *(const float4*)(xs2 + (size_t)v0.x * 16 + q * 4);
        float w0 = __int_as_float(v0.y);
        a0.x += w0 * x0.x; a0.y += w0 * x0.y; a0.z += w0 * x0.z; a0.w += w0 * x0.w;
    }
    a0.x += a1.x; a0.y += a1.y; a0.z += a1.z; a0.w += a1.w;
#pragma unroll
    for (int m = 4; m <= 32; m <<= 1) {        // reduce across 16 slots
        a0.x += __shfl_xor(a0.x, m);
        a0.y += __shfl_xor(a0.y, m);
        a0.z += __shfl_xor(a0.z, m);
        a0.w += __shfl_xor(a0.w, m);
    }

    if (slot == 0) {
        float d = dis[node];
        float4 self = *(const float4*)(xs2 + (size_t)node * 16 + q * 4);
        float4 bb   = *(const float4*)(b2 + q * 4);
        float4 o;
        o.x = d * (a0.x + self.x) + bb.x;
        o.y = d * (a0.y + self.y) + bb.y;
        o.z = d * (a0.z + self.z) + bb.z;
        o.w = d * (a0.w + self.w) + bb.w;
        *(float4*)(out + (size_t)node * 16 + q * 4) = o;
    }
}

extern "C" void kernel_launch(void* const* d_in, const int* in_sizes, int n_in,
                              void* d_out, int out_size, void* d_ws, size_t ws_size,
                              hipStream_t stream) {
    const float* x  = (const float*)d_in[0];
    const int*   ei = (const int*)d_in[1];   // [2, E] int32
    const float* ew = (const float*)d_in[2];
    const float* W1 = (const float*)d_in[3];
    const float* b1 = (const float*)d_in[4];
    const float* W2 = (const float*)d_in[5];
    const float* b2 = (const float*)d_in[6];
    float* out = (float*)d_out;

    const int N = in_sizes[0] / 16;
    const int E = in_sizes[2];
    const int* row = ei;
    const int* col = ei + E;

    const int nbuck = (N + BS - 1) / BS;          // 1563
    const int per   = (E + CHUNKS - 1) / CHUNKS;
    const int nb    = (nbuck + 255) / 256;        // 7

    // workspace layout (4B units)
    //  [0, 2E)   : rw2 (node-sorted int2)
    //  [2E, 4E)  : rw (bucket-sorted int2), DEAD after nodesort;
    //              reused: xsc [16N] at 2E, t [16N], xs2 [16N]  (48N <= 2E)
    //  [4E, ...) : dis[N], ptr[BS*nbuck+1], part, base, tot, start, bsum
    float* ws    = (float*)d_ws;
    int2*  rw2   = (int2*)ws;
    int2*  rw    = (int2*)(ws + (size_t)2 * E);
    float* xsc   = ws + (size_t)2 * E;
    float* tbuf  = xsc + (size_t)N * 16;
    float* xs2   = tbuf + (size_t)N * 16;
    float* dis   = ws + (size_t)4 * E;
    int*   ptr   = (int*)(dis + N);
    int*   part  = ptr + (size_t)BS * nbuck + 1;
    int*   base  = part + (size_t)CHUNKS * nbuck;
    int*   tot   = base + (size_t)CHUNKS * nbuck;
    int*   start = tot + nbuck;
    int*   bsum  = start + nbuck + 1;

    hist_kernel<<<CHUNKS, 1024, nbuck * 4, stream>>>(col, part, E, nbuck, per);
    colscan_kernel<<<nbuck, 64, 0, stream>>>(part, base, tot, nbuck);
    scan1_kernel<<<nb, 256, 0, stream>>>(tot, start, bsum, nbuck);
    scan2_kernel<<<1, 512, 0, stream>>>(bsum, nb);
    scan3_kernel<<<(nbuck + 256) / 256 + 1, 256, 0, stream>>>(start, bsum, nbuck, E);
    place_kernel<<<CHUNKS, 1024, 2 * nbuck * 4, stream>>>(row, col, ew, start, base, rw, E, nbuck, per);
    nodesort_kernel<<<nbuck, 512, 0, stream>>>(rw, start, rw2, ptr, dis, N, E, nbuck);

    xsc_kernel<<<(N * 4 + 255) / 256, 256, 0, stream>>>(x, dis, xsc, N);
    gather1_kernel<<<(N + 3) / 4, 256, 0, stream>>>(ptr, rw2, xsc, dis, tbuf, N);
    mlp_kernel<<<(N + 255) / 256, 256, 0, stream>>>(tbuf, dis, W1, b1, W2, xs2, N);
    gather2_kernel<<<(N + 3) / 4, 256, 0, stream>>>(ptr, rw2, xs2, dis, b2, out, N);
}

// Round 10
// 199.241 us; speedup vs baseline: 1.2550x; 1.2550x over previous
//
#include <hip/hip_runtime.h>
#include <cstdint>

// ---------------------------------------------------------------------------
// 2-layer GCN, zero scattered global atomics, per-node CSR gather.
// CSR build uses 256-node buckets + 256 chunks so bucket-sorted writes land
// in ~256 B runs (full-line L2 write-back, ~1x write amplification).
//
//  K1 hist:     per-chunk LDS histogram of bucket=col>>8 -> part[C][NB]
//  K2 colscan:  per-bucket scan over chunks -> base[C][NB], tot[NB]
//  scan1/2/3:   exclusive scan tot -> start[NB+1]
//  K4 place:    rw[pos] = {row | cl<<20, ew}  (bucket-sorted, 256B runs)
//  K5 nodesort: per-bucket count + LDS scan -> ptr[node], dis=rsqrt(deg+1),
//               rw2 = node-sorted edge list (64KB window, L2-merged writes)
//  K6 xsc:      xsc = x * dis                                   [N,16]
//  K7 gather1:  wave/node: t = dis*(sum w*xsc[r] + xsc_self)    [N,16]
//  K8 mlp:      xs2 = (relu(t@W1^T + b1) @ W2^T) * dis          [N,16]
//  K9 gather2:  wave/node: out = dis*(sum w*xs2[r] + xs2_self)+b2
// ---------------------------------------------------------------------------

#define BS 256          // nodes per bucket
#define CHUNKS 256      // edge chunks for hist/place

// nontemporal 8B edge-record load (int2 not accepted by the builtin directly)
__device__ __forceinline__ int2 nt_load_edge(const int2* p) {
    long long v = __builtin_nontemporal_load((const long long*)p);
    int2 r;
    r.x = (int)(v & 0xFFFFFFFFll);
    r.y = (int)(v >> 32);
    return r;
}

__global__ __launch_bounds__(1024) void hist_kernel(
        const int* __restrict__ col, int* __restrict__ part,
        int E, int nbuck, int per) {
    extern __shared__ int sh[];
    for (int t = threadIdx.x; t < nbuck; t += blockDim.x) sh[t] = 0;
    __syncthreads();
    int lo = blockIdx.x * per, hi = min(E, lo + per);
    for (int e = lo + threadIdx.x; e < hi; e += blockDim.x)
        atomicAdd(&sh[col[e] >> 8], 1);
    __syncthreads();
    for (int t = threadIdx.x; t < nbuck; t += blockDim.x)
        part[(size_t)blockIdx.x * nbuck + t] = sh[t];
}

__global__ void colscan_kernel(const int* __restrict__ part, int* __restrict__ base,
                               int* __restrict__ tot, int nbuck) {
    int b = blockIdx.x;
    if (b >= nbuck) return;
    int lane = threadIdx.x;  // 64
    int off = 0;
    for (int g = 0; g < CHUNKS; g += 64) {
        int c = g + lane;
        int v = part[(size_t)c * nbuck + b];
        int s = v;
        #pragma unroll
        for (int d = 1; d < 64; d <<= 1) {
            int t = __shfl_up(s, d);
            if (lane >= d) s += t;
        }
        base[(size_t)c * nbuck + b] = off + (s - v);
        off += __shfl(s, 63);
    }
    if (lane == 0) tot[b] = off;
}

__global__ void scan1_kernel(const int* __restrict__ cnt, int* __restrict__ excl,
                             int* __restrict__ bsum, int n) {
    __shared__ int s[256];
    int tid = threadIdx.x;
    int i = blockIdx.x * 256 + tid;
    int v = (i < n) ? cnt[i] : 0;
    s[tid] = v;
    __syncthreads();
    for (int off = 1; off < 256; off <<= 1) {
        int t = (tid >= off) ? s[tid - off] : 0;
        __syncthreads();
        s[tid] += t;
        __syncthreads();
    }
    if (i < n) excl[i] = s[tid] - v;
    if (tid == 255) bsum[blockIdx.x] = s[255];
}

__global__ void scan2_kernel(int* __restrict__ bsum, int nb) {
    __shared__ int s[512];
    int tid = threadIdx.x;
    int v = (tid < nb) ? bsum[tid] : 0;
    s[tid] = v;
    __syncthreads();
    for (int off = 1; off < 512; off <<= 1) {
        int t = (tid >= off) ? s[tid - off] : 0;
        __syncthreads();
        s[tid] += t;
        __syncthreads();
    }
    if (tid < nb) bsum[tid] = s[tid] - v;
}

__global__ void scan3_kernel(int* __restrict__ excl, const int* __restrict__ bsum,
                             int n, int E) {
    int i = blockIdx.x * 256 + threadIdx.x;
    if (i < n) excl[i] += bsum[i >> 8];
    else if (i == n) excl[n] = E;
}

__global__ __launch_bounds__(1024) void place_kernel(
        const int* __restrict__ row, const int* __restrict__ col,
        const float* __restrict__ ew,
        const int* __restrict__ start, const int* __restrict__ base,
        int2* __restrict__ rw, int E, int nbuck, int per) {
    extern __shared__ int sh[];
    int* lbase = sh;          // nbuck
    int* cnt2  = sh + nbuck;  // nbuck
    int c = blockIdx.x;
    for (int t = threadIdx.x; t < nbuck; t += blockDim.x) {
        lbase[t] = start[t] + base[(size_t)c * nbuck + t];
        cnt2[t] = 0;
    }
    __syncthreads();
    int lo = c * per, hi = min(E, lo + per);
    for (int e = lo + threadIdx.x; e < hi; e += blockDim.x) {
        int cc = col[e];
        int b = cc >> 8;
        int p = lbase[b] + atomicAdd(&cnt2[b], 1);
        int2 v;
        v.x = row[e] | ((cc & 255) << 20);   // row < 2^20 (N = 100K)
        v.y = __float_as_int(ew[e]);
        rw[p] = v;
    }
}

// per-bucket (256 nodes): counts -> LDS scan -> ptr, dis; node-sorted rw2
__global__ __launch_bounds__(512) void nodesort_kernel(
        const int2* __restrict__ rw, const int* __restrict__ start,
        int2* __restrict__ rw2, int* __restrict__ ptr,
        float* __restrict__ dis, int N, int E, int nbuck) {
    __shared__ int cnt[BS];
    __shared__ float fdeg[BS];
    __shared__ int fill[BS];
    __shared__ int stmp[BS];
    int b = blockIdx.x, tid = threadIdx.x;
    for (int t = tid; t < BS; t += 512) { cnt[t] = 0; fdeg[t] = 0.f; }
    __syncthreads();
    int s0 = start[b], s1 = start[b + 1];
    for (int e = s0 + tid; e < s1; e += 512) {
        int2 v = rw[e];
        int cl = v.x >> 20;
        atomicAdd(&cnt[cl], 1);
        atomicAdd(&fdeg[cl], __int_as_float(v.y));
    }
    __syncthreads();

    // Hillis-Steele inclusive scan of cnt[256] in LDS
    int myc = 0;
    if (tid < BS) { myc = cnt[tid]; stmp[tid] = myc; }
    __syncthreads();
    for (int off = 1; off < BS; off <<= 1) {
        int t = 0;
        if (tid < BS && tid >= off) t = stmp[tid - off];
        __syncthreads();
        if (tid < BS) stmp[tid] += t;
        __syncthreads();
    }
    if (tid < BS) {
        int excl = stmp[tid] - myc;
        ptr[b * BS + tid] = s0 + excl;
        fill[tid] = excl;
        int node = b * BS + tid;
        if (node < N) dis[node] = rsqrtf(fdeg[tid] + 1.0f);
    }
    __syncthreads();

    for (int e = s0 + tid; e < s1; e += 512) {
        int2 v = rw[e];
        int cl = v.x >> 20;
        int p = s0 + atomicAdd(&fill[cl], 1);
        int2 o;
        o.x = v.x & 0xFFFFF;
        o.y = v.y;
        rw2[p] = o;
    }
    if (b == 0 && tid == 0) ptr[nbuck * BS] = E;
}

// xsc = x * dis   (one float4 per thread)
__global__ void xsc_kernel(const float* __restrict__ x, const float* __restrict__ dis,
                           float* __restrict__ xsc, int N) {
    int gid = blockIdx.x * 256 + threadIdx.x;
    if (gid >= N * 4) return;
    int node = gid >> 2;
    float d = dis[node];
    float4 v = ((const float4*)x)[gid];
    v.x *= d; v.y *= d; v.z *= d; v.w *= d;
    ((float4*)xsc)[gid] = v;
}

// wave per node; lane = slot(16) x quad(4); 16 edges/iter, 64 B gathers.
// src: gather table [N,16]; writes dst = dis*(agg + src_self)   (pure gather)
__global__ __launch_bounds__(256) void gather1_kernel(
        const int* __restrict__ ptr, const int2* __restrict__ rw2,
        const float* __restrict__ src, const float* __restrict__ dis,
        float* __restrict__ dst, int N) {
    int node = (blockIdx.x * 256 + threadIdx.x) >> 6;
    int lane = threadIdx.x & 63;
    int slot = lane >> 2;          // 16 edge slots
    int q    = lane & 3;           // 4 float4 quads = 16 features
    if (node >= N) return;
    int s0 = ptr[node], s1 = ptr[node + 1];

    float4 a0 = {0.f, 0.f, 0.f, 0.f}, a1 = {0.f, 0.f, 0.f, 0.f};
    int e = s0 + slot;
    for (; e + 16 < s1; e += 32) {             // 2-way unroll, stride 16/slot
        int2 v0 = nt_load_edge(&rw2[e]);
        int2 v1 = nt_load_edge(&rw2[e + 16]);
        float4 x0 = *(const float4*)(src + (size_t)v0.x * 16 + q * 4);
        float4 x1 = *(const float4*)(src + (size_t)v1.x * 16 + q * 4);
        float w0 = __int_as_float(v0.y), w1 = __int_as_float(v1.y);
        a0.x += w0 * x0.x; a0.y += w0 * x0.y; a0.z += w0 * x0.z; a0.w += w0 * x0.w;
        a1.x += w1 * x1.x; a1.y += w1 * x1.y; a1.z += w1 * x1.z; a1.w += w1 * x1.w;
    }
    if (e < s1) {
        int2 v0 = nt_load_edge(&rw2[e]);
        float4 x0 = *(const float4*)(src + (size_t)v0.x * 16 + q * 4);
        float w0 = __int_as_float(v0.y);
        a0.x += w0 * x0.x; a0.y += w0 * x0.y; a0.z += w0 * x0.z; a0.w += w0 * x0.w;
    }
    a0.x += a1.x; a0.y += a1.y; a0.z += a1.z; a0.w += a1.w;
#pragma unroll
    for (int m = 4; m <= 32; m <<= 1) {        // reduce across 16 slots
        a0.x += __shfl_xor(a0.x, m);
        a0.y += __shfl_xor(a0.y, m);
        a0.z += __shfl_xor(a0.z, m);
        a0.w += __shfl_xor(a0.w, m);
    }

    if (slot == 0) {
        float d = dis[node];
        float4 self = *(const float4*)(src + (size_t)node * 16 + q * 4);
        float4 o;
        o.x = d * (a0.x + self.x);
        o.y = d * (a0.y + self.y);
        o.z = d * (a0.z + self.z);
        o.w = d * (a0.w + self.w);
        *(float4*)(dst + (size_t)node * 16 + q * 4) = o;
    }
}

// xs2 = (relu(t @ W1^T + b1) @ W2^T) * dis, thread per node, regs only.
__global__ __launch_bounds__(256) void mlp_kernel(
        const float* __restrict__ t, const float* __restrict__ dis,
        const float* __restrict__ W1, const float* __restrict__ b1,
        const float* __restrict__ W2, float* __restrict__ xs2, int N) {
    __shared__ float sW1[512];
    __shared__ float sW2[512];
    __shared__ float sb1[32];
    for (int k = threadIdx.x; k < 512; k += 256) {
        sW1[k] = W1[k];
        sW2[k] = W2[k];
    }
    if (threadIdx.x < 32) sb1[threadIdx.x] = b1[threadIdx.x];
    __syncthreads();
    int i = blockIdx.x * 256 + threadIdx.x;
    if (i >= N) return;

    float tr[16];
#pragma unroll
    for (int k = 0; k < 4; ++k) {
        float4 v = ((const float4*)(t + (size_t)i * 16))[k];
        tr[4*k+0] = v.x; tr[4*k+1] = v.y; tr[4*k+2] = v.z; tr[4*k+3] = v.w;
    }
    float h[32];
#pragma unroll
    for (int o = 0; o < 32; ++o) {
        float acc = sb1[o];
#pragma unroll
        for (int k = 0; k < 16; ++k) acc += tr[k] * sW1[o * 16 + k];
        h[o] = fmaxf(acc, 0.f);
    }
    float d = dis[i];
    float* outp = xs2 + (size_t)i * 16;
#pragma unroll
    for (int o = 0; o < 16; ++o) {
        float acc = 0.f;
#pragma unroll
        for (int k = 0; k < 32; ++k) acc += h[k] * sW2[o * 32 + k];
        outp[o] = acc * d;
    }
}

// wave per node; same gather shape; final epilogue adds b2.
__global__ __launch_bounds__(256) void gather2_kernel(
        const int* __restrict__ ptr, const int2* __restrict__ rw2,
        const float* __restrict__ xs2, const float* __restrict__ dis,
        const float* __restrict__ b2, float* __restrict__ out, int N) {
    int node = (blockIdx.x * 256 + threadIdx.x) >> 6;
    int lane = threadIdx.x & 63;
    int slot = lane >> 2;          // 16 edge slots
    int q    = lane & 3;           // 4 float4 quads = 16 features
    if (node >= N) return;
    int s0 = ptr[node], s1 = ptr[node + 1];

    float4 a0 = {0.f, 0.f, 0.f, 0.f}, a1 = {0.f, 0.f, 0.f, 0.f};
    int e = s0 + slot;
    for (; e + 16 < s1; e += 32) {             // 2-way unroll, stride 16/slot
        int2 v0 = nt_load_edge(&rw2[e]);
        int2 v1 = nt_load_edge(&rw2[e + 16]);
        float4 x0 = *(const float4*)(xs2 + (size_t)v0.x * 16 + q * 4);
        float4 x1 = *(const float4*)(xs2 + (size_t)v1.x * 16 + q * 4);
        float w0 = __int_as_float(v0.y), w1 = __int_as_float(v1.y);
        a0.x += w0 * x0.x; a0.y += w0 * x0.y; a0.z += w0 * x0.z; a0.w += w0 * x0.w;
        a1.x += w1 * x1.x; a1.y += w1 * x1.y; a1.z += w1 * x1.z; a1.w += w1 * x1.w;
    }
    if (e < s1) {
        int2 v0 = nt_load_edge(&rw2[e]);
        float4 x0 = *(const float4*)(xs2 + (size_t)v0.x * 16 + q * 4);
        float w0 = __int_as_float(v0.y);
        a0.x += w0 * x0.x; a0.y += w0 * x0.y; a0.z += w0 * x0.z; a0.w += w0 * x0.w;
    }
    a0.x += a1.x; a0.y += a1.y; a0.z += a1.z; a0.w += a1.w;
#pragma unroll
    for (int m = 4; m <= 32; m <<= 1) {        // reduce across 16 slots
        a0.x += __shfl_xor(a0.x, m);
        a0.y += __shfl_xor(a0.y, m);
        a0.z += __shfl_xor(a0.z, m);
        a0.w += __shfl_xor(a0.w, m);
    }

    if (slot == 0) {
        float d = dis[node];
        float4 self = *(const float4*)(xs2 + (size_t)node * 16 + q * 4);
        float4 bb   = *(const float4*)(b2 + q * 4);
        float4 o;
        o.x = d * (a0.x + self.x) + bb.x;
        o.y = d * (a0.y + self.y) + bb.y;
        o.z = d * (a0.z + self.z) + bb.z;
        o.w = d * (a0.w + self.w) + bb.w;
        *(float4*)(out + (size_t)node * 16 + q * 4) = o;
    }
}

extern "C" void kernel_launch(void* const* d_in, const int* in_sizes, int n_in,
                              void* d_out, int out_size, void* d_ws, size_t ws_size,
                              hipStream_t stream) {
    const float* x  = (const float*)d_in[0];
    const int*   ei = (const int*)d_in[1];   // [2, E] int32
    const float* ew = (const float*)d_in[2];
    const float* W1 = (const float*)d_in[3];
    const float* b1 = (const float*)d_in[4];
    const float* W2 = (const float*)d_in[5];
    const float* b2 = (const float*)d_in[6];
    float* out = (float*)d_out;

    const int N = in_sizes[0] / 16;
    const int E = in_sizes[2];
    const int* row = ei;
    const int* col = ei + E;

    const int nbuck = (N + BS - 1) / BS;          // 391
    const int per   = (E + CHUNKS - 1) / CHUNKS;  // 12500
    const int nb    = (nbuck + 255) / 256;        // 2

    // workspace layout (4B units)
    //  [0, 2E)   : rw2 (node-sorted int2)
    //  [2E, 4E)  : rw (bucket-sorted int2), DEAD after nodesort;
    //              reused: xsc [16N] at 2E, t [16N], xs2 [16N]  (48N <= 2E)
    //  [4E, ...) : dis[N], ptr[BS*nbuck+1], part, base, tot, start, bsum
    float* ws    = (float*)d_ws;
    int2*  rw2   = (int2*)ws;
    int2*  rw    = (int2*)(ws + (size_t)2 * E);
    float* xsc   = ws + (size_t)2 * E;
    float* tbuf  = xsc + (size_t)N * 16;
    float* xs2   = tbuf + (size_t)N * 16;
    float* dis   = ws + (size_t)4 * E;
    int*   ptr   = (int*)(dis + N);
    int*   part  = ptr + (size_t)BS * nbuck + 1;
    int*   base  = part + (size_t)CHUNKS * nbuck;
    int*   tot   = base + (size_t)CHUNKS * nbuck;
    int*   start = tot + nbuck;
    int*   bsum  = start + nbuck + 1;

    hist_kernel<<<CHUNKS, 1024, nbuck * 4, stream>>>(col, part, E, nbuck, per);
    colscan_kernel<<<nbuck, 64, 0, stream>>>(part, base, tot, nbuck);
    scan1_kernel<<<nb, 256, 0, stream>>>(tot, start, bsum, nbuck);
    scan2_kernel<<<1, 512, 0, stream>>>(bsum, nb);
    scan3_kernel<<<(nbuck + 256) / 256 + 1, 256, 0, stream>>>(start, bsum, nbuck, E);
    place_kernel<<<CHUNKS, 1024, 2 * nbuck * 4, stream>>>(row, col, ew, start, base, rw, E, nbuck, per);
    nodesort_kernel<<<nbuck, 512, 0, stream>>>(rw, start, rw2, ptr, dis, N, E, nbuck);

    xsc_kernel<<<(N * 4 + 255) / 256, 256, 0, stream>>>(x, dis, xsc, N);
    gather1_kernel<<<(N + 3) / 4, 256, 0, stream>>>(ptr, rw2, xsc, dis, tbuf, N);
    mlp_kernel<<<(N + 255) / 256, 256, 0, stream>>>(tbuf, dis, W1, b1, W2, xs2, N);
    gather2_kernel<<<(N + 3) / 4, 256, 0, stream>>>(ptr, rw2, xs2, dis, b2, out, N);
}

// Round 11
// 192.666 us; speedup vs baseline: 1.2978x; 1.0341x over previous
//
#include <hip/hip_runtime.h>
#include <hip/hip_fp16.h>
#include <cstdint>

// ---------------------------------------------------------------------------
// 2-layer GCN, zero scattered global atomics, per-node CSR gather.
// Gather tables (xsc, xs2) are fp16 [N,16] = 3.2 MB -> fit per-XCD 4 MiB L2;
// gathers read 32 B/edge. Accumulation/MLP/outputs stay fp32.
//
//  K1 hist:     per-chunk LDS histogram of bucket=col>>8 -> part[C][NB]
//  K2 colscan:  per-bucket scan over chunks -> base[C][NB], tot[NB]
//  scan1/2/3:   exclusive scan tot -> start[NB+1]
//  K4 place:    rw[pos] = {row | cl<<20, ew}  (bucket-sorted, 256B runs)
//  K5 nodesort: per-bucket count + LDS scan -> ptr[node], dis=rsqrt(deg+1),
//               rw2 = node-sorted edge list
//  K6 xsc:      xsc = fp16(x * dis)                              [N,16] h
//  K7 gather1:  wave/node: t = dis*(sum w*xsc[r] + xsc_self)     [N,16] f32
//  K8 mlp:      xs2 = fp16((relu(t@W1^T + b1) @ W2^T) * dis)     [N,16] h
//  K9 gather2:  wave/node: out = dis*(sum w*xs2[r] + xs2_self)+b2
// ---------------------------------------------------------------------------

#define BS 256          // nodes per bucket
#define CHUNKS 256      // edge chunks for hist/place

// nontemporal 8B edge-record load (int2 not accepted by the builtin directly)
__device__ __forceinline__ int2 nt_load_edge(const int2* p) {
    long long v = __builtin_nontemporal_load((const long long*)p);
    int2 r;
    r.x = (int)(v & 0xFFFFFFFFll);
    r.y = (int)(v >> 32);
    return r;
}

// 4 fp16 -> 4 fp32 from an 8B-aligned half pointer
__device__ __forceinline__ float4 load_h4(const __half* p) {
    uint2 u = *(const uint2*)p;
    __half2 p0 = *(__half2*)&u.x;
    __half2 p1 = *(__half2*)&u.y;
    float2 f0 = __half22float2(p0);
    float2 f1 = __half22float2(p1);
    float4 r;
    r.x = f0.x; r.y = f0.y; r.z = f1.x; r.w = f1.y;
    return r;
}

__global__ __launch_bounds__(1024) void hist_kernel(
        const int* __restrict__ col, int* __restrict__ part,
        int E, int nbuck, int per) {
    extern __shared__ int sh[];
    for (int t = threadIdx.x; t < nbuck; t += blockDim.x) sh[t] = 0;
    __syncthreads();
    int lo = blockIdx.x * per, hi = min(E, lo + per);
    for (int e = lo + threadIdx.x; e < hi; e += blockDim.x)
        atomicAdd(&sh[col[e] >> 8], 1);
    __syncthreads();
    for (int t = threadIdx.x; t < nbuck; t += blockDim.x)
        part[(size_t)blockIdx.x * nbuck + t] = sh[t];
}

__global__ void colscan_kernel(const int* __restrict__ part, int* __restrict__ base,
                               int* __restrict__ tot, int nbuck) {
    int b = blockIdx.x;
    if (b >= nbuck) return;
    int lane = threadIdx.x;  // 64
    int off = 0;
    for (int g = 0; g < CHUNKS; g += 64) {
        int c = g + lane;
        int v = part[(size_t)c * nbuck + b];
        int s = v;
        #pragma unroll
        for (int d = 1; d < 64; d <<= 1) {
            int t = __shfl_up(s, d);
            if (lane >= d) s += t;
        }
        base[(size_t)c * nbuck + b] = off + (s - v);
        off += __shfl(s, 63);
    }
    if (lane == 0) tot[b] = off;
}

__global__ void scan1_kernel(const int* __restrict__ cnt, int* __restrict__ excl,
                             int* __restrict__ bsum, int n) {
    __shared__ int s[256];
    int tid = threadIdx.x;
    int i = blockIdx.x * 256 + tid;
    int v = (i < n) ? cnt[i] : 0;
    s[tid] = v;
    __syncthreads();
    for (int off = 1; off < 256; off <<= 1) {
        int t = (tid >= off) ? s[tid - off] : 0;
        __syncthreads();
        s[tid] += t;
        __syncthreads();
    }
    if (i < n) excl[i] = s[tid] - v;
    if (tid == 255) bsum[blockIdx.x] = s[255];
}

__global__ void scan2_kernel(int* __restrict__ bsum, int nb) {
    __shared__ int s[512];
    int tid = threadIdx.x;
    int v = (tid < nb) ? bsum[tid] : 0;
    s[tid] = v;
    __syncthreads();
    for (int off = 1; off < 512; off <<= 1) {
        int t = (tid >= off) ? s[tid - off] : 0;
        __syncthreads();
        s[tid] += t;
        __syncthreads();
    }
    if (tid < nb) bsum[tid] = s[tid] - v;
}

__global__ void scan3_kernel(int* __restrict__ excl, const int* __restrict__ bsum,
                             int n, int E) {
    int i = blockIdx.x * 256 + threadIdx.x;
    if (i < n) excl[i] += bsum[i >> 8];
    else if (i == n) excl[n] = E;
}

__global__ __launch_bounds__(1024) void place_kernel(
        const int* __restrict__ row, const int* __restrict__ col,
        const float* __restrict__ ew,
        const int* __restrict__ start, const int* __restrict__ base,
        int2* __restrict__ rw, int E, int nbuck, int per) {
    extern __shared__ int sh[];
    int* lbase = sh;          // nbuck
    int* cnt2  = sh + nbuck;  // nbuck
    int c = blockIdx.x;
    for (int t = threadIdx.x; t < nbuck; t += blockDim.x) {
        lbase[t] = start[t] + base[(size_t)c * nbuck + t];
        cnt2[t] = 0;
    }
    __syncthreads();
    int lo = c * per, hi = min(E, lo + per);
    for (int e = lo + threadIdx.x; e < hi; e += blockDim.x) {
        int cc = col[e];
        int b = cc >> 8;
        int p = lbase[b] + atomicAdd(&cnt2[b], 1);
        int2 v;
        v.x = row[e] | ((cc & 255) << 20);   // row < 2^20 (N = 100K)
        v.y = __float_as_int(ew[e]);
        rw[p] = v;
    }
}

// per-bucket (256 nodes): counts -> LDS scan -> ptr, dis; node-sorted rw2
__global__ __launch_bounds__(512) void nodesort_kernel(
        const int2* __restrict__ rw, const int* __restrict__ start,
        int2* __restrict__ rw2, int* __restrict__ ptr,
        float* __restrict__ dis, int N, int E, int nbuck) {
    __shared__ int cnt[BS];
    __shared__ float fdeg[BS];
    __shared__ int fill[BS];
    __shared__ int stmp[BS];
    int b = blockIdx.x, tid = threadIdx.x;
    for (int t = tid; t < BS; t += 512) { cnt[t] = 0; fdeg[t] = 0.f; }
    __syncthreads();
    int s0 = start[b], s1 = start[b + 1];
    for (int e = s0 + tid; e < s1; e += 512) {
        int2 v = rw[e];
        int cl = v.x >> 20;
        atomicAdd(&cnt[cl], 1);
        atomicAdd(&fdeg[cl], __int_as_float(v.y));
    }
    __syncthreads();

    // Hillis-Steele inclusive scan of cnt[256] in LDS
    int myc = 0;
    if (tid < BS) { myc = cnt[tid]; stmp[tid] = myc; }
    __syncthreads();
    for (int off = 1; off < BS; off <<= 1) {
        int t = 0;
        if (tid < BS && tid >= off) t = stmp[tid - off];
        __syncthreads();
        if (tid < BS) stmp[tid] += t;
        __syncthreads();
    }
    if (tid < BS) {
        int excl = stmp[tid] - myc;
        ptr[b * BS + tid] = s0 + excl;
        fill[tid] = excl;
        int node = b * BS + tid;
        if (node < N) dis[node] = rsqrtf(fdeg[tid] + 1.0f);
    }
    __syncthreads();

    for (int e = s0 + tid; e < s1; e += 512) {
        int2 v = rw[e];
        int cl = v.x >> 20;
        int p = s0 + atomicAdd(&fill[cl], 1);
        int2 o;
        o.x = v.x & 0xFFFFF;
        o.y = v.y;
        rw2[p] = o;
    }
    if (b == 0 && tid == 0) ptr[nbuck * BS] = E;
}

// xsc = fp16(x * dis)   (thread per node, 2x uint4 stores)
__global__ void xsc_kernel(const float* __restrict__ x, const float* __restrict__ dis,
                           __half* __restrict__ xsc, int N) {
    int i = blockIdx.x * 256 + threadIdx.x;
    if (i >= N) return;
    float d = dis[i];
    const float4* xr = (const float4*)(x + (size_t)i * 16);
    __half2 h[8];
#pragma unroll
    for (int k = 0; k < 4; ++k) {
        float4 v = xr[k];
        h[2*k]   = __floats2half2_rn(v.x * d, v.y * d);
        h[2*k+1] = __floats2half2_rn(v.z * d, v.w * d);
    }
    uint4* dst = (uint4*)(xsc + (size_t)i * 16);
    dst[0] = *(uint4*)&h[0];
    dst[1] = *(uint4*)&h[4];
}

// wave per node; lane = slot(16) x quad(4); 16 edges/iter, 32 B fp16 gathers.
// writes dst (fp32) = dis*(agg + src_self)
__global__ __launch_bounds__(256) void gather1_kernel(
        const int* __restrict__ ptr, const int2* __restrict__ rw2,
        const __half* __restrict__ src, const float* __restrict__ dis,
        float* __restrict__ dst, int N) {
    int node = (blockIdx.x * 256 + threadIdx.x) >> 6;
    int lane = threadIdx.x & 63;
    int slot = lane >> 2;          // 16 edge slots
    int q    = lane & 3;           // 4 quads of 4 halves = 16 features
    if (node >= N) return;
    int s0 = ptr[node], s1 = ptr[node + 1];

    float4 a0 = {0.f, 0.f, 0.f, 0.f}, a1 = {0.f, 0.f, 0.f, 0.f};
    int e = s0 + slot;
    for (; e + 16 < s1; e += 32) {             // 2-way unroll, stride 16/slot
        int2 v0 = nt_load_edge(&rw2[e]);
        int2 v1 = nt_load_edge(&rw2[e + 16]);
        float4 x0 = load_h4(src + (size_t)v0.x * 16 + q * 4);
        float4 x1 = load_h4(src + (size_t)v1.x * 16 + q * 4);
        float w0 = __int_as_float(v0.y), w1 = __int_as_float(v1.y);
        a0.x += w0 * x0.x; a0.y += w0 * x0.y; a0.z += w0 * x0.z; a0.w += w0 * x0.w;
        a1.x += w1 * x1.x; a1.y += w1 * x1.y; a1.z += w1 * x1.z; a1.w += w1 * x1.w;
    }
    if (e < s1) {
        int2 v0 = nt_load_edge(&rw2[e]);
        float4 x0 = load_h4(src + (size_t)v0.x * 16 + q * 4);
        float w0 = __int_as_float(v0.y);
        a0.x += w0 * x0.x; a0.y += w0 * x0.y; a0.z += w0 * x0.z; a0.w += w0 * x0.w;
    }
    a0.x += a1.x; a0.y += a1.y; a0.z += a1.z; a0.w += a1.w;
#pragma unroll
    for (int m = 4; m <= 32; m <<= 1) {        // reduce across 16 slots
        a0.x += __shfl_xor(a0.x, m);
        a0.y += __shfl_xor(a0.y, m);
        a0.z += __shfl_xor(a0.z, m);
        a0.w += __shfl_xor(a0.w, m);
    }

    if (slot == 0) {
        float d = dis[node];
        float4 self = load_h4(src + (size_t)node * 16 + q * 4);
        float4 o;
        o.x = d * (a0.x + self.x);
        o.y = d * (a0.y + self.y);
        o.z = d * (a0.z + self.z);
        o.w = d * (a0.w + self.w);
        *(float4*)(dst + (size_t)node * 16 + q * 4) = o;
    }
}

// xs2 = fp16((relu(t @ W1^T + b1) @ W2^T) * dis), thread per node, regs only.
__global__ __launch_bounds__(256) void mlp_kernel(
        const float* __restrict__ t, const float* __restrict__ dis,
        const float* __restrict__ W1, const float* __restrict__ b1,
        const float* __restrict__ W2, __half* __restrict__ xs2, int N) {
    __shared__ float sW1[512];
    __shared__ float sW2[512];
    __shared__ float sb1[32];
    for (int k = threadIdx.x; k < 512; k += 256) {
        sW1[k] = W1[k];
        sW2[k] = W2[k];
    }
    if (threadIdx.x < 32) sb1[threadIdx.x] = b1[threadIdx.x];
    __syncthreads();
    int i = blockIdx.x * 256 + threadIdx.x;
    if (i >= N) return;

    float tr[16];
#pragma unroll
    for (int k = 0; k < 4; ++k) {
        float4 v = ((const float4*)(t + (size_t)i * 16))[k];
        tr[4*k+0] = v.x; tr[4*k+1] = v.y; tr[4*k+2] = v.z; tr[4*k+3] = v.w;
    }
    float h[32];
#pragma unroll
    for (int o = 0; o < 32; ++o) {
        float acc = sb1[o];
#pragma unroll
        for (int k = 0; k < 16; ++k) acc += tr[k] * sW1[o * 16 + k];
        h[o] = fmaxf(acc, 0.f);
    }
    float d = dis[i];
    float o16[16];
#pragma unroll
    for (int o = 0; o < 16; ++o) {
        float acc = 0.f;
#pragma unroll
        for (int k = 0; k < 32; ++k) acc += h[k] * sW2[o * 32 + k];
        o16[o] = acc * d;
    }
    __half2 hh[8];
#pragma unroll
    for (int k = 0; k < 8; ++k) hh[k] = __floats2half2_rn(o16[2*k], o16[2*k+1]);
    uint4* dst = (uint4*)(xs2 + (size_t)i * 16);
    dst[0] = *(uint4*)&hh[0];
    dst[1] = *(uint4*)&hh[4];
}

// wave per node; same gather shape; final epilogue adds b2 (fp32 out).
__global__ __launch_bounds__(256) void gather2_kernel(
        const int* __restrict__ ptr, const int2* __restrict__ rw2,
        const __half* __restrict__ xs2, const float* __restrict__ dis,
        const float* __restrict__ b2, float* __restrict__ out, int N) {
    int node = (blockIdx.x * 256 + threadIdx.x) >> 6;
    int lane = threadIdx.x & 63;
    int slot = lane >> 2;          // 16 edge slots
    int q    = lane & 3;           // 4 quads of 4 halves = 16 features
    if (node >= N) return;
    int s0 = ptr[node], s1 = ptr[node + 1];

    float4 a0 = {0.f, 0.f, 0.f, 0.f}, a1 = {0.f, 0.f, 0.f, 0.f};
    int e = s0 + slot;
    for (; e + 16 < s1; e += 32) {             // 2-way unroll, stride 16/slot
        int2 v0 = nt_load_edge(&rw2[e]);
        int2 v1 = nt_load_edge(&rw2[e + 16]);
        float4 x0 = load_h4(xs2 + (size_t)v0.x * 16 + q * 4);
        float4 x1 = load_h4(xs2 + (size_t)v1.x * 16 + q * 4);
        float w0 = __int_as_float(v0.y), w1 = __int_as_float(v1.y);
        a0.x += w0 * x0.x; a0.y += w0 * x0.y; a0.z += w0 * x0.z; a0.w += w0 * x0.w;
        a1.x += w1 * x1.x; a1.y += w1 * x1.y; a1.z += w1 * x1.z; a1.w += w1 * x1.w;
    }
    if (e < s1) {
        int2 v0 = nt_load_edge(&rw2[e]);
        float4 x0 = load_h4(xs2 + (size_t)v0.x * 16 + q * 4);
        float w0 = __int_as_float(v0.y);
        a0.x += w0 * x0.x; a0.y += w0 * x0.y; a0.z += w0 * x0.z; a0.w += w0 * x0.w;
    }
    a0.x += a1.x; a0.y += a1.y; a0.z += a1.z; a0.w += a1.w;
#pragma unroll
    for (int m = 4; m <= 32; m <<= 1) {        // reduce across 16 slots
        a0.x += __shfl_xor(a0.x, m);
        a0.y += __shfl_xor(a0.y, m);
        a0.z += __shfl_xor(a0.z, m);
        a0.w += __shfl_xor(a0.w, m);
    }

    if (slot == 0) {
        float d = dis[node];
        float4 self = load_h4(xs2 + (size_t)node * 16 + q * 4);
        float4 bb   = *(const float4*)(b2 + q * 4);
        float4 o;
        o.x = d * (a0.x + self.x) + bb.x;
        o.y = d * (a0.y + self.y) + bb.y;
        o.z = d * (a0.z + self.z) + bb.z;
        o.w = d * (a0.w + self.w) + bb.w;
        *(float4*)(out + (size_t)node * 16 + q * 4) = o;
    }
}

extern "C" void kernel_launch(void* const* d_in, const int* in_sizes, int n_in,
                              void* d_out, int out_size, void* d_ws, size_t ws_size,
                              hipStream_t stream) {
    const float* x  = (const float*)d_in[0];
    const int*   ei = (const int*)d_in[1];   // [2, E] int32
    const float* ew = (const float*)d_in[2];
    const float* W1 = (const float*)d_in[3];
    const float* b1 = (const float*)d_in[4];
    const float* W2 = (const float*)d_in[5];
    const float* b2 = (const float*)d_in[6];
    float* out = (float*)d_out;

    const int N = in_sizes[0] / 16;
    const int E = in_sizes[2];
    const int* row = ei;
    const int* col = ei + E;

    const int nbuck = (N + BS - 1) / BS;          // 391
    const int per   = (E + CHUNKS - 1) / CHUNKS;  // 12500
    const int nb    = (nbuck + 255) / 256;        // 2

    // workspace layout (4B units)
    //  [0, 2E)   : rw2 (node-sorted int2)
    //  [2E, 4E)  : rw (bucket-sorted int2), DEAD after nodesort; reused:
    //              xsc half[16N] (8N units) at 2E
    //              tbuf f32[16N] (16N units) at 2E+8N
    //              xs2 half[16N] (8N units) at 2E+24N      (32N <= 2E ok)
    //  [4E, ...) : dis[N], ptr[BS*nbuck+1], part, base, tot, start, bsum
    float*  ws    = (float*)d_ws;
    int2*   rw2   = (int2*)ws;
    int2*   rw    = (int2*)(ws + (size_t)2 * E);
    __half* xsc   = (__half*)(ws + (size_t)2 * E);
    float*  tbuf  = ws + (size_t)2 * E + (size_t)8 * N;
    __half* xs2   = (__half*)(ws + (size_t)2 * E + (size_t)24 * N);
    float*  dis   = ws + (size_t)4 * E;
    int*    ptr   = (int*)(dis + N);
    int*    part  = ptr + (size_t)BS * nbuck + 1;
    int*    base  = part + (size_t)CHUNKS * nbuck;
    int*    tot   = base + (size_t)CHUNKS * nbuck;
    int*    start = tot + nbuck;
    int*    bsum  = start + nbuck + 1;

    hist_kernel<<<CHUNKS, 1024, nbuck * 4, stream>>>(col, part, E, nbuck, per);
    colscan_kernel<<<nbuck, 64, 0, stream>>>(part, base, tot, nbuck);
    scan1_kernel<<<nb, 256, 0, stream>>>(tot, start, bsum, nbuck);
    scan2_kernel<<<1, 512, 0, stream>>>(bsum, nb);
    scan3_kernel<<<(nbuck + 256) / 256 + 1, 256, 0, stream>>>(start, bsum, nbuck, E);
    place_kernel<<<CHUNKS, 1024, 2 * nbuck * 4, stream>>>(row, col, ew, start, base, rw, E, nbuck, per);
    nodesort_kernel<<<nbuck, 512, 0, stream>>>(rw, start, rw2, ptr, dis, N, E, nbuck);

    xsc_kernel<<<(N + 255) / 256, 256, 0, stream>>>(x, dis, xsc, N);
    gather1_kernel<<<(N + 3) / 4, 256, 0, stream>>>(ptr, rw2, xsc, dis, tbuf, N);
    mlp_kernel<<<(N + 255) / 256, 256, 0, stream>>>(tbuf, dis, W1, b1, W2, xs2, N);
    gather2_kernel<<<(N + 3) / 4, 256, 0, stream>>>(ptr, rw2, xs2, dis, b2, out, N);
}

// Round 12
// 191.121 us; speedup vs baseline: 1.3083x; 1.0081x over previous
//
#include <hip/hip_runtime.h>
#include <hip/hip_fp16.h>
#include <cstdint>

// ---------------------------------------------------------------------------
// 2-layer GCN, zero scattered global atomics, per-node CSR gather.
// Gather tables (xsc, xs2) are fp16 [N,16] = 3.2 MB (L2-resident).
// Gather kernels: 1024-thread blocks = 16 waves = 16 consecutive nodes;
// the block's contiguous edge window is staged into LDS with coalesced
// bursts, so the only long-latency dependent load left is the table gather.
//
//  K1 hist:     per-chunk LDS histogram of bucket=col>>8 -> part[C][NB]
//  K2 colscan:  per-bucket scan over chunks -> base[C][NB], tot[NB]
//  scan1/2/3:   exclusive scan tot -> start[NB+1]
//  K4 place:    rw[pos] = {row | cl<<20, ew}  (bucket-sorted, 256B runs)
//  K5 nodesort: per-bucket count + LDS scan -> ptr[node], dis=rsqrt(deg+1),
//               rw2 = node-sorted edge list
//  K6 xsc:      xsc = fp16(x * dis)                              [N,16] h
//  K7 gather1:  t = dis*(sum w*xsc[r] + xsc_self)                [N,16] f32
//  K8 mlp:      xs2 = fp16((relu(t@W1^T + b1) @ W2^T) * dis)     [N,16] h
//  K9 gather2:  out = dis*(sum w*xs2[r] + xs2_self)+b2
// ---------------------------------------------------------------------------

#define BS 256          // nodes per bucket (CSR build)
#define CHUNKS 256      // edge chunks for hist/place
#define GNODES 16       // nodes per gather block (16 waves)
#define GCAP 2048       // staged edges per gather block (16 KB LDS)

__device__ __forceinline__ int2 nt_load_edge(const int2* p) {
    long long v = __builtin_nontemporal_load((const long long*)p);
    int2 r;
    r.x = (int)(v & 0xFFFFFFFFll);
    r.y = (int)(v >> 32);
    return r;
}

// 4 fp16 -> 4 fp32 from an 8B-aligned half pointer
__device__ __forceinline__ float4 load_h4(const __half* p) {
    uint2 u = *(const uint2*)p;
    __half2 p0 = *(__half2*)&u.x;
    __half2 p1 = *(__half2*)&u.y;
    float2 f0 = __half22float2(p0);
    float2 f1 = __half22float2(p1);
    float4 r;
    r.x = f0.x; r.y = f0.y; r.z = f1.x; r.w = f1.y;
    return r;
}

__global__ __launch_bounds__(1024) void hist_kernel(
        const int* __restrict__ col, int* __restrict__ part,
        int E, int nbuck, int per) {
    extern __shared__ int sh[];
    for (int t = threadIdx.x; t < nbuck; t += blockDim.x) sh[t] = 0;
    __syncthreads();
    int lo = blockIdx.x * per, hi = min(E, lo + per);
    for (int e = lo + threadIdx.x; e < hi; e += blockDim.x)
        atomicAdd(&sh[col[e] >> 8], 1);
    __syncthreads();
    for (int t = threadIdx.x; t < nbuck; t += blockDim.x)
        part[(size_t)blockIdx.x * nbuck + t] = sh[t];
}

__global__ void colscan_kernel(const int* __restrict__ part, int* __restrict__ base,
                               int* __restrict__ tot, int nbuck) {
    int b = blockIdx.x;
    if (b >= nbuck) return;
    int lane = threadIdx.x;  // 64
    int off = 0;
    for (int g = 0; g < CHUNKS; g += 64) {
        int c = g + lane;
        int v = part[(size_t)c * nbuck + b];
        int s = v;
        #pragma unroll
        for (int d = 1; d < 64; d <<= 1) {
            int t = __shfl_up(s, d);
            if (lane >= d) s += t;
        }
        base[(size_t)c * nbuck + b] = off + (s - v);
        off += __shfl(s, 63);
    }
    if (lane == 0) tot[b] = off;
}

__global__ void scan1_kernel(const int* __restrict__ cnt, int* __restrict__ excl,
                             int* __restrict__ bsum, int n) {
    __shared__ int s[256];
    int tid = threadIdx.x;
    int i = blockIdx.x * 256 + tid;
    int v = (i < n) ? cnt[i] : 0;
    s[tid] = v;
    __syncthreads();
    for (int off = 1; off < 256; off <<= 1) {
        int t = (tid >= off) ? s[tid - off] : 0;
        __syncthreads();
        s[tid] += t;
        __syncthreads();
    }
    if (i < n) excl[i] = s[tid] - v;
    if (tid == 255) bsum[blockIdx.x] = s[255];
}

__global__ void scan2_kernel(int* __restrict__ bsum, int nb) {
    __shared__ int s[512];
    int tid = threadIdx.x;
    int v = (tid < nb) ? bsum[tid] : 0;
    s[tid] = v;
    __syncthreads();
    for (int off = 1; off < 512; off <<= 1) {
        int t = (tid >= off) ? s[tid - off] : 0;
        __syncthreads();
        s[tid] += t;
        __syncthreads();
    }
    if (tid < nb) bsum[tid] = s[tid] - v;
}

__global__ void scan3_kernel(int* __restrict__ excl, const int* __restrict__ bsum,
                             int n, int E) {
    int i = blockIdx.x * 256 + threadIdx.x;
    if (i < n) excl[i] += bsum[i >> 8];
    else if (i == n) excl[n] = E;
}

__global__ __launch_bounds__(1024) void place_kernel(
        const int* __restrict__ row, const int* __restrict__ col,
        const float* __restrict__ ew,
        const int* __restrict__ start, const int* __restrict__ base,
        int2* __restrict__ rw, int E, int nbuck, int per) {
    extern __shared__ int sh[];
    int* lbase = sh;          // nbuck
    int* cnt2  = sh + nbuck;  // nbuck
    int c = blockIdx.x;
    for (int t = threadIdx.x; t < nbuck; t += blockDim.x) {
        lbase[t] = start[t] + base[(size_t)c * nbuck + t];
        cnt2[t] = 0;
    }
    __syncthreads();
    int lo = c * per, hi = min(E, lo + per);
    for (int e = lo + threadIdx.x; e < hi; e += blockDim.x) {
        int cc = col[e];
        int b = cc >> 8;
        int p = lbase[b] + atomicAdd(&cnt2[b], 1);
        int2 v;
        v.x = row[e] | ((cc & 255) << 20);   // row < 2^20 (N = 100K)
        v.y = __float_as_int(ew[e]);
        rw[p] = v;
    }
}

// per-bucket (256 nodes): counts -> LDS scan -> ptr, dis; node-sorted rw2
__global__ __launch_bounds__(512) void nodesort_kernel(
        const int2* __restrict__ rw, const int* __restrict__ start,
        int2* __restrict__ rw2, int* __restrict__ ptr,
        float* __restrict__ dis, int N, int E, int nbuck) {
    __shared__ int cnt[BS];
    __shared__ float fdeg[BS];
    __shared__ int fill[BS];
    __shared__ int stmp[BS];
    int b = blockIdx.x, tid = threadIdx.x;
    for (int t = tid; t < BS; t += 512) { cnt[t] = 0; fdeg[t] = 0.f; }
    __syncthreads();
    int s0 = start[b], s1 = start[b + 1];
    for (int e = s0 + tid; e < s1; e += 512) {
        int2 v = rw[e];
        int cl = v.x >> 20;
        atomicAdd(&cnt[cl], 1);
        atomicAdd(&fdeg[cl], __int_as_float(v.y));
    }
    __syncthreads();

    // Hillis-Steele inclusive scan of cnt[256] in LDS
    int myc = 0;
    if (tid < BS) { myc = cnt[tid]; stmp[tid] = myc; }
    __syncthreads();
    for (int off = 1; off < BS; off <<= 1) {
        int t = 0;
        if (tid < BS && tid >= off) t = stmp[tid - off];
        __syncthreads();
        if (tid < BS) stmp[tid] += t;
        __syncthreads();
    }
    if (tid < BS) {
        int excl = stmp[tid] - myc;
        ptr[b * BS + tid] = s0 + excl;
        fill[tid] = excl;
        int node = b * BS + tid;
        if (node < N) dis[node] = rsqrtf(fdeg[tid] + 1.0f);
    }
    __syncthreads();

    for (int e = s0 + tid; e < s1; e += 512) {
        int2 v = rw[e];
        int cl = v.x >> 20;
        int p = s0 + atomicAdd(&fill[cl], 1);
        int2 o;
        o.x = v.x & 0xFFFFF;
        o.y = v.y;
        rw2[p] = o;
    }
    if (b == 0 && tid == 0) ptr[nbuck * BS] = E;
}

// xsc = fp16(x * dis)
__global__ void xsc_kernel(const float* __restrict__ x, const float* __restrict__ dis,
                           __half* __restrict__ xsc, int N) {
    int i = blockIdx.x * 256 + threadIdx.x;
    if (i >= N) return;
    float d = dis[i];
    const float4* xr = (const float4*)(x + (size_t)i * 16);
    __half2 h[8];
#pragma unroll
    for (int k = 0; k < 4; ++k) {
        float4 v = xr[k];
        h[2*k]   = __floats2half2_rn(v.x * d, v.y * d);
        h[2*k+1] = __floats2half2_rn(v.z * d, v.w * d);
    }
    uint4* dst = (uint4*)(xsc + (size_t)i * 16);
    dst[0] = *(uint4*)&h[0];
    dst[1] = *(uint4*)&h[4];
}

// 16 waves = 16 nodes per block; block edge window staged in LDS.
// lane = slot(16) x quad(4); 16 edges/iter/wave, 2-way unroll.
// FINAL selects epilogue: 0 -> dst_f = dis*(agg+self); 1 -> dst_f += b2
template <int FINAL>
__global__ __launch_bounds__(1024) void gather_kernel(
        const int* __restrict__ ptr, const int2* __restrict__ rw2,
        const __half* __restrict__ src, const float* __restrict__ dis,
        const float* __restrict__ b2, float* __restrict__ dst, int N) {
    __shared__ int2 se[GCAP];
    __shared__ int sptr[GNODES + 1];
    int tid = threadIdx.x;
    int base = blockIdx.x * GNODES;
    if (tid <= GNODES) sptr[tid] = ptr[base + tid];
    __syncthreads();
    int w0 = sptr[0];
    int count = min(sptr[GNODES] - w0, GCAP);
    for (int i = tid; i < count; i += 1024)
        se[i] = nt_load_edge(&rw2[w0 + i]);
    __syncthreads();

    int wave = tid >> 6;
    int node = base + wave;
    if (node >= N) return;
    int lane = tid & 63;
    int slot = lane >> 2;          // 16 edge slots
    int q    = lane & 3;           // 4 quads of 4 halves = 16 features
    int s0 = sptr[wave], s1 = sptr[wave + 1];

    float4 a0 = {0.f, 0.f, 0.f, 0.f}, a1 = {0.f, 0.f, 0.f, 0.f};
    int e = s0 + slot;
    for (; e + 16 < s1; e += 32) {             // 2-way unroll, stride 16/slot
        int li0 = e - w0, li1 = li0 + 16;
        int2 v0 = (li0 < GCAP) ? se[li0] : nt_load_edge(&rw2[e]);
        int2 v1 = (li1 < GCAP) ? se[li1] : nt_load_edge(&rw2[e + 16]);
        float4 x0 = load_h4(src + (size_t)v0.x * 16 + q * 4);
        float4 x1 = load_h4(src + (size_t)v1.x * 16 + q * 4);
        float w0f = __int_as_float(v0.y), w1f = __int_as_float(v1.y);
        a0.x += w0f * x0.x; a0.y += w0f * x0.y; a0.z += w0f * x0.z; a0.w += w0f * x0.w;
        a1.x += w1f * x1.x; a1.y += w1f * x1.y; a1.z += w1f * x1.z; a1.w += w1f * x1.w;
    }
    if (e < s1) {
        int li = e - w0;
        int2 v0 = (li < GCAP) ? se[li] : nt_load_edge(&rw2[e]);
        float4 x0 = load_h4(src + (size_t)v0.x * 16 + q * 4);
        float w0f = __int_as_float(v0.y);
        a0.x += w0f * x0.x; a0.y += w0f * x0.y; a0.z += w0f * x0.z; a0.w += w0f * x0.w;
    }
    a0.x += a1.x; a0.y += a1.y; a0.z += a1.z; a0.w += a1.w;
#pragma unroll
    for (int m = 4; m <= 32; m <<= 1) {        // reduce across 16 slots
        a0.x += __shfl_xor(a0.x, m);
        a0.y += __shfl_xor(a0.y, m);
        a0.z += __shfl_xor(a0.z, m);
        a0.w += __shfl_xor(a0.w, m);
    }

    if (slot == 0) {
        float d = dis[node];
        float4 self = load_h4(src + (size_t)node * 16 + q * 4);
        float4 o;
        o.x = d * (a0.x + self.x);
        o.y = d * (a0.y + self.y);
        o.z = d * (a0.z + self.z);
        o.w = d * (a0.w + self.w);
        if (FINAL) {
            float4 bb = *(const float4*)(b2 + q * 4);
            o.x += bb.x; o.y += bb.y; o.z += bb.z; o.w += bb.w;
        }
        *(float4*)(dst + (size_t)node * 16 + q * 4) = o;
    }
}

// xs2 = fp16((relu(t @ W1^T + b1) @ W2^T) * dis), thread per node, regs only.
__global__ __launch_bounds__(256) void mlp_kernel(
        const float* __restrict__ t, const float* __restrict__ dis,
        const float* __restrict__ W1, const float* __restrict__ b1,
        const float* __restrict__ W2, __half* __restrict__ xs2, int N) {
    __shared__ float sW1[512];
    __shared__ float sW2[512];
    __shared__ float sb1[32];
    for (int k = threadIdx.x; k < 512; k += 256) {
        sW1[k] = W1[k];
        sW2[k] = W2[k];
    }
    if (threadIdx.x < 32) sb1[threadIdx.x] = b1[threadIdx.x];
    __syncthreads();
    int i = blockIdx.x * 256 + threadIdx.x;
    if (i >= N) return;

    float tr[16];
#pragma unroll
    for (int k = 0; k < 4; ++k) {
        float4 v = ((const float4*)(t + (size_t)i * 16))[k];
        tr[4*k+0] = v.x; tr[4*k+1] = v.y; tr[4*k+2] = v.z; tr[4*k+3] = v.w;
    }
    float h[32];
#pragma unroll
    for (int o = 0; o < 32; ++o) {
        float acc = sb1[o];
#pragma unroll
        for (int k = 0; k < 16; ++k) acc += tr[k] * sW1[o * 16 + k];
        h[o] = fmaxf(acc, 0.f);
    }
    float d = dis[i];
    float o16[16];
#pragma unroll
    for (int o = 0; o < 16; ++o) {
        float acc = 0.f;
#pragma unroll
        for (int k = 0; k < 32; ++k) acc += h[k] * sW2[o * 32 + k];
        o16[o] = acc * d;
    }
    __half2 hh[8];
#pragma unroll
    for (int k = 0; k < 8; ++k) hh[k] = __floats2half2_rn(o16[2*k], o16[2*k+1]);
    uint4* dst = (uint4*)(xs2 + (size_t)i * 16);
    dst[0] = *(uint4*)&hh[0];
    dst[1] = *(uint4*)&hh[4];
}

// tbuf (f32 [N,16]) -> fp16 table is produced by mlp directly; gather2 output
// goes to `out` with FINAL=1 epilogue.

extern "C" void kernel_launch(void* const* d_in, const int* in_sizes, int n_in,
                              void* d_out, int out_size, void* d_ws, size_t ws_size,
                              hipStream_t stream) {
    const float* x  = (const float*)d_in[0];
    const int*   ei = (const int*)d_in[1];   // [2, E] int32
    const float* ew = (const float*)d_in[2];
    const float* W1 = (const float*)d_in[3];
    const float* b1 = (const float*)d_in[4];
    const float* W2 = (const float*)d_in[5];
    const float* b2 = (const float*)d_in[6];
    float* out = (float*)d_out;

    const int N = in_sizes[0] / 16;
    const int E = in_sizes[2];
    const int* row = ei;
    const int* col = ei + E;

    const int nbuck = (N + BS - 1) / BS;          // 391
    const int per   = (E + CHUNKS - 1) / CHUNKS;  // 12500
    const int nb    = (nbuck + 255) / 256;        // 2

    // workspace layout (4B units)
    //  [0, 2E)   : rw2 (node-sorted int2)
    //  [2E, 4E)  : rw (bucket-sorted int2), DEAD after nodesort; reused:
    //              xsc half[16N] (8N units) at 2E
    //              tbuf f32[16N] (16N units) at 2E+8N
    //              xs2 half[16N] (8N units) at 2E+24N      (32N <= 2E ok)
    //  [4E, ...) : dis[N], ptr[BS*nbuck+1], part, base, tot, start, bsum
    float*  ws    = (float*)d_ws;
    int2*   rw2   = (int2*)ws;
    int2*   rw    = (int2*)(ws + (size_t)2 * E);
    __half* xsc   = (__half*)(ws + (size_t)2 * E);
    float*  tbuf  = ws + (size_t)2 * E + (size_t)8 * N;
    __half* xs2   = (__half*)(ws + (size_t)2 * E + (size_t)24 * N);
    float*  dis   = ws + (size_t)4 * E;
    int*    ptr   = (int*)(dis + N);
    int*    part  = ptr + (size_t)BS * nbuck + 1;
    int*    base  = part + (size_t)CHUNKS * nbuck;
    int*    tot   = base + (size_t)CHUNKS * nbuck;
    int*    start = tot + nbuck;
    int*    bsum  = start + nbuck + 1;

    hist_kernel<<<CHUNKS, 1024, nbuck * 4, stream>>>(col, part, E, nbuck, per);
    colscan_kernel<<<nbuck, 64, 0, stream>>>(part, base, tot, nbuck);
    scan1_kernel<<<nb, 256, 0, stream>>>(tot, start, bsum, nbuck);
    scan2_kernel<<<1, 512, 0, stream>>>(bsum, nb);
    scan3_kernel<<<(nbuck + 256) / 256 + 1, 256, 0, stream>>>(start, bsum, nbuck, E);
    place_kernel<<<CHUNKS, 1024, 2 * nbuck * 4, stream>>>(row, col, ew, start, base, rw, E, nbuck, per);
    nodesort_kernel<<<nbuck, 512, 0, stream>>>(rw, start, rw2, ptr, dis, N, E, nbuck);

    xsc_kernel<<<(N + 255) / 256, 256, 0, stream>>>(x, dis, xsc, N);
    {
        int gblocks = (N + GNODES - 1) / GNODES;
        gather_kernel<0><<<gblocks, 1024, 0, stream>>>(ptr, rw2, xsc, dis, b2, tbuf, N);
        mlp_kernel<<<(N + 255) / 256, 256, 0, stream>>>(tbuf, dis, W1, b1, W2, xs2, N);
        gather_kernel<1><<<gblocks, 1024, 0, stream>>>(ptr, rw2, xs2, dis, b2, out, N);
    }
}

// Round 13
// 177.882 us; speedup vs baseline: 1.4057x; 1.0744x over previous
//
#include <hip/hip_runtime.h>
#include <hip/hip_fp16.h>
#include <cstdint>

// ---------------------------------------------------------------------------
// 2-layer GCN, zero scattered global atomics, per-node CSR gather.
// Gather tables (xsc, xs2) are fp16 [N,16] = 3.2 MB (L2-resident).
// Gather kernels: 4 nodes per wave (avg degree = 32), lane = grp(4) x
// slot(4) x quad(4); ~8 edges/lane, 2-way unrolled -> sustained MLP.
// rw2.x holds the pre-scaled byte offset (node*32) to cut addressing VALU.
//
//  K1 hist:     per-chunk LDS histogram of bucket=col>>8 -> part[C][NB]
//  K2 colscan:  per-bucket scan over chunks -> base[C][NB], tot[NB]
//  scan1/2/3:   exclusive scan tot -> start[NB+1]
//  K4 place:    rw[pos] = {row | cl<<20, ew}  (bucket-sorted, 256B runs)
//  K5 nodesort: per-bucket count + LDS scan -> ptr[node], dis=rsqrt(deg+1),
//               rw2 = node-sorted edge list {row*32, ew}
//  K6 xsc:      xsc = fp16(x * dis)                              [N,16] h
//  K7 gather1:  t = dis*(sum w*xsc[r] + xsc_self)                [N,16] f32
//  K8 mlp:      xs2 = fp16((relu(t@W1^T + b1) @ W2^T) * dis)     [N,16] h
//  K9 gather2:  out = dis*(sum w*xs2[r] + xs2_self)+b2
// ---------------------------------------------------------------------------

#define BS 256          // nodes per bucket (CSR build)
#define CHUNKS 256      // edge chunks for hist/place

__device__ __forceinline__ int2 nt_load_edge(const int2* p) {
    long long v = __builtin_nontemporal_load((const long long*)p);
    int2 r;
    r.x = (int)(v & 0xFFFFFFFFll);
    r.y = (int)(v >> 32);
    return r;
}

// 4 fp16 -> 4 fp32 from an 8B-aligned half pointer
__device__ __forceinline__ float4 load_h4(const __half* p) {
    uint2 u = *(const uint2*)p;
    __half2 p0 = *(__half2*)&u.x;
    __half2 p1 = *(__half2*)&u.y;
    float2 f0 = __half22float2(p0);
    float2 f1 = __half22float2(p1);
    float4 r;
    r.x = f0.x; r.y = f0.y; r.z = f1.x; r.w = f1.y;
    return r;
}

__global__ __launch_bounds__(1024) void hist_kernel(
        const int* __restrict__ col, int* __restrict__ part,
        int E, int nbuck, int per) {
    extern __shared__ int sh[];
    for (int t = threadIdx.x; t < nbuck; t += blockDim.x) sh[t] = 0;
    __syncthreads();
    int lo = blockIdx.x * per, hi = min(E, lo + per);
    for (int e = lo + threadIdx.x; e < hi; e += blockDim.x)
        atomicAdd(&sh[col[e] >> 8], 1);
    __syncthreads();
    for (int t = threadIdx.x; t < nbuck; t += blockDim.x)
        part[(size_t)blockIdx.x * nbuck + t] = sh[t];
}

__global__ void colscan_kernel(const int* __restrict__ part, int* __restrict__ base,
                               int* __restrict__ tot, int nbuck) {
    int b = blockIdx.x;
    if (b >= nbuck) return;
    int lane = threadIdx.x;  // 64
    int off = 0;
    for (int g = 0; g < CHUNKS; g += 64) {
        int c = g + lane;
        int v = part[(size_t)c * nbuck + b];
        int s = v;
        #pragma unroll
        for (int d = 1; d < 64; d <<= 1) {
            int t = __shfl_up(s, d);
            if (lane >= d) s += t;
        }
        base[(size_t)c * nbuck + b] = off + (s - v);
        off += __shfl(s, 63);
    }
    if (lane == 0) tot[b] = off;
}

__global__ void scan1_kernel(const int* __restrict__ cnt, int* __restrict__ excl,
                             int* __restrict__ bsum, int n) {
    __shared__ int s[256];
    int tid = threadIdx.x;
    int i = blockIdx.x * 256 + tid;
    int v = (i < n) ? cnt[i] : 0;
    s[tid] = v;
    __syncthreads();
    for (int off = 1; off < 256; off <<= 1) {
        int t = (tid >= off) ? s[tid - off] : 0;
        __syncthreads();
        s[tid] += t;
        __syncthreads();
    }
    if (i < n) excl[i] = s[tid] - v;
    if (tid == 255) bsum[blockIdx.x] = s[255];
}

__global__ void scan2_kernel(int* __restrict__ bsum, int nb) {
    __shared__ int s[512];
    int tid = threadIdx.x;
    int v = (tid < nb) ? bsum[tid] : 0;
    s[tid] = v;
    __syncthreads();
    for (int off = 1; off < 512; off <<= 1) {
        int t = (tid >= off) ? s[tid - off] : 0;
        __syncthreads();
        s[tid] += t;
        __syncthreads();
    }
    if (tid < nb) bsum[tid] = s[tid] - v;
}

__global__ void scan3_kernel(int* __restrict__ excl, const int* __restrict__ bsum,
                             int n, int E) {
    int i = blockIdx.x * 256 + threadIdx.x;
    if (i < n) excl[i] += bsum[i >> 8];
    else if (i == n) excl[n] = E;
}

__global__ __launch_bounds__(1024) void place_kernel(
        const int* __restrict__ row, const int* __restrict__ col,
        const float* __restrict__ ew,
        const int* __restrict__ start, const int* __restrict__ base,
        int2* __restrict__ rw, int E, int nbuck, int per) {
    extern __shared__ int sh[];
    int* lbase = sh;          // nbuck
    int* cnt2  = sh + nbuck;  // nbuck
    int c = blockIdx.x;
    for (int t = threadIdx.x; t < nbuck; t += blockDim.x) {
        lbase[t] = start[t] + base[(size_t)c * nbuck + t];
        cnt2[t] = 0;
    }
    __syncthreads();
    int lo = c * per, hi = min(E, lo + per);
    for (int e = lo + threadIdx.x; e < hi; e += blockDim.x) {
        int cc = col[e];
        int b = cc >> 8;
        int p = lbase[b] + atomicAdd(&cnt2[b], 1);
        int2 v;
        v.x = row[e] | ((cc & 255) << 20);   // row < 2^20 (N = 100K)
        v.y = __float_as_int(ew[e]);
        rw[p] = v;
    }
}

// per-bucket (256 nodes): counts -> LDS scan -> ptr, dis; node-sorted rw2
// rw2.x = row * 32 (byte offset into the fp16 [N,16] table)
__global__ __launch_bounds__(512) void nodesort_kernel(
        const int2* __restrict__ rw, const int* __restrict__ start,
        int2* __restrict__ rw2, int* __restrict__ ptr,
        float* __restrict__ dis, int N, int E, int nbuck) {
    __shared__ int cnt[BS];
    __shared__ float fdeg[BS];
    __shared__ int fill[BS];
    __shared__ int stmp[BS];
    int b = blockIdx.x, tid = threadIdx.x;
    for (int t = tid; t < BS; t += 512) { cnt[t] = 0; fdeg[t] = 0.f; }
    __syncthreads();
    int s0 = start[b], s1 = start[b + 1];
    for (int e = s0 + tid; e < s1; e += 512) {
        int2 v = rw[e];
        int cl = v.x >> 20;
        atomicAdd(&cnt[cl], 1);
        atomicAdd(&fdeg[cl], __int_as_float(v.y));
    }
    __syncthreads();

    // Hillis-Steele inclusive scan of cnt[256] in LDS
    int myc = 0;
    if (tid < BS) { myc = cnt[tid]; stmp[tid] = myc; }
    __syncthreads();
    for (int off = 1; off < BS; off <<= 1) {
        int t = 0;
        if (tid < BS && tid >= off) t = stmp[tid - off];
        __syncthreads();
        if (tid < BS) stmp[tid] += t;
        __syncthreads();
    }
    if (tid < BS) {
        int excl = stmp[tid] - myc;
        ptr[b * BS + tid] = s0 + excl;
        fill[tid] = excl;
        int node = b * BS + tid;
        if (node < N) dis[node] = rsqrtf(fdeg[tid] + 1.0f);
    }
    __syncthreads();

    for (int e = s0 + tid; e < s1; e += 512) {
        int2 v = rw[e];
        int cl = v.x >> 20;
        int p = s0 + atomicAdd(&fill[cl], 1);
        int2 o;
        o.x = (v.x & 0xFFFFF) << 5;   // byte offset = row * 32
        o.y = v.y;
        rw2[p] = o;
    }
    if (b == 0 && tid == 0) ptr[nbuck * BS] = E;
}

// xsc = fp16(x * dis)
__global__ void xsc_kernel(const float* __restrict__ x, const float* __restrict__ dis,
                           __half* __restrict__ xsc, int N) {
    int i = blockIdx.x * 256 + threadIdx.x;
    if (i >= N) return;
    float d = dis[i];
    const float4* xr = (const float4*)(x + (size_t)i * 16);
    __half2 h[8];
#pragma unroll
    for (int k = 0; k < 4; ++k) {
        float4 v = xr[k];
        h[2*k]   = __floats2half2_rn(v.x * d, v.y * d);
        h[2*k+1] = __floats2half2_rn(v.z * d, v.w * d);
    }
    uint4* dst = (uint4*)(xsc + (size_t)i * 16);
    dst[0] = *(uint4*)&h[0];
    dst[1] = *(uint4*)&h[4];
}

// 4 nodes per wave: lane = grp(4) x slot(4) x quad(4).
// Each 16-lane group owns one node; slots stride 4 through its edges.
// FINAL=0: dst = dis*(agg+self); FINAL=1: dst = dis*(agg+self)+b2.
template <int FINAL>
__global__ __launch_bounds__(256) void gather_kernel(
        const int* __restrict__ ptr, const int2* __restrict__ rw2,
        const __half* __restrict__ src, const float* __restrict__ dis,
        const float* __restrict__ b2, float* __restrict__ dst, int N) {
    int tid  = threadIdx.x;
    int wave = tid >> 6;
    int lane = tid & 63;
    int g = lane >> 4;            // node group within wave
    int s = (lane >> 2) & 3;      // 4 edge slots per node
    int q = lane & 3;             // 4 quads of 4 halves = 16 features
    int node = (blockIdx.x * 4 + wave) * 4 + g;
    if (node >= N) return;
    int s0 = ptr[node], s1 = ptr[node + 1];

    const char* srcb = (const char*)src;
    float4 a0 = {0.f, 0.f, 0.f, 0.f}, a1 = {0.f, 0.f, 0.f, 0.f};
    int e = s0 + s;
    for (; e + 4 < s1; e += 8) {               // 2-way unroll, stride 4/slot
        int2 v0 = nt_load_edge(&rw2[e]);
        int2 v1 = nt_load_edge(&rw2[e + 4]);
        float4 x0 = load_h4((const __half*)(srcb + v0.x) + q * 4);
        float4 x1 = load_h4((const __half*)(srcb + v1.x) + q * 4);
        float w0 = __int_as_float(v0.y), w1 = __int_as_float(v1.y);
        a0.x += w0 * x0.x; a0.y += w0 * x0.y; a0.z += w0 * x0.z; a0.w += w0 * x0.w;
        a1.x += w1 * x1.x; a1.y += w1 * x1.y; a1.z += w1 * x1.z; a1.w += w1 * x1.w;
    }
    if (e < s1) {
        int2 v0 = nt_load_edge(&rw2[e]);
        float4 x0 = load_h4((const __half*)(srcb + v0.x) + q * 4);
        float w0 = __int_as_float(v0.y);
        a0.x += w0 * x0.x; a0.y += w0 * x0.y; a0.z += w0 * x0.z; a0.w += w0 * x0.w;
    }
    a0.x += a1.x; a0.y += a1.y; a0.z += a1.z; a0.w += a1.w;
#pragma unroll
    for (int m = 4; m <= 8; m <<= 1) {         // reduce across 4 slots
        a0.x += __shfl_xor(a0.x, m);
        a0.y += __shfl_xor(a0.y, m);
        a0.z += __shfl_xor(a0.z, m);
        a0.w += __shfl_xor(a0.w, m);
    }

    if (s == 0) {
        float d = dis[node];
        float4 self = load_h4((const __half*)(srcb + ((size_t)node << 5)) + q * 4);
        float4 o;
        o.x = d * (a0.x + self.x);
        o.y = d * (a0.y + self.y);
        o.z = d * (a0.z + self.z);
        o.w = d * (a0.w + self.w);
        if (FINAL) {
            float4 bb = *(const float4*)(b2 + q * 4);
            o.x += bb.x; o.y += bb.y; o.z += bb.z; o.w += bb.w;
        }
        *(float4*)(dst + (size_t)node * 16 + q * 4) = o;
    }
}

// xs2 = fp16((relu(t @ W1^T + b1) @ W2^T) * dis), thread per node, regs only.
__global__ __launch_bounds__(256) void mlp_kernel(
        const float* __restrict__ t, const float* __restrict__ dis,
        const float* __restrict__ W1, const float* __restrict__ b1,
        const float* __restrict__ W2, __half* __restrict__ xs2, int N) {
    __shared__ float sW1[512];
    __shared__ float sW2[512];
    __shared__ float sb1[32];
    for (int k = threadIdx.x; k < 512; k += 256) {
        sW1[k] = W1[k];
        sW2[k] = W2[k];
    }
    if (threadIdx.x < 32) sb1[threadIdx.x] = b1[threadIdx.x];
    __syncthreads();
    int i = blockIdx.x * 256 + threadIdx.x;
    if (i >= N) return;

    float tr[16];
#pragma unroll
    for (int k = 0; k < 4; ++k) {
        float4 v = ((const float4*)(t + (size_t)i * 16))[k];
        tr[4*k+0] = v.x; tr[4*k+1] = v.y; tr[4*k+2] = v.z; tr[4*k+3] = v.w;
    }
    float h[32];
#pragma unroll
    for (int o = 0; o < 32; ++o) {
        float acc = sb1[o];
#pragma unroll
        for (int k = 0; k < 16; ++k) acc += tr[k] * sW1[o * 16 + k];
        h[o] = fmaxf(acc, 0.f);
    }
    float d = dis[i];
    float o16[16];
#pragma unroll
    for (int o = 0; o < 16; ++o) {
        float acc = 0.f;
#pragma unroll
        for (int k = 0; k < 32; ++k) acc += h[k] * sW2[o * 32 + k];
        o16[o] = acc * d;
    }
    __half2 hh[8];
#pragma unroll
    for (int k = 0; k < 8; ++k) hh[k] = __floats2half2_rn(o16[2*k], o16[2*k+1]);
    uint4* dst = (uint4*)(xs2 + (size_t)i * 16);
    dst[0] = *(uint4*)&hh[0];
    dst[1] = *(uint4*)&hh[4];
}

extern "C" void kernel_launch(void* const* d_in, const int* in_sizes, int n_in,
                              void* d_out, int out_size, void* d_ws, size_t ws_size,
                              hipStream_t stream) {
    const float* x  = (const float*)d_in[0];
    const int*   ei = (const int*)d_in[1];   // [2, E] int32
    const float* ew = (const float*)d_in[2];
    const float* W1 = (const float*)d_in[3];
    const float* b1 = (const float*)d_in[4];
    const float* W2 = (const float*)d_in[5];
    const float* b2 = (const float*)d_in[6];
    float* out = (float*)d_out;

    const int N = in_sizes[0] / 16;
    const int E = in_sizes[2];
    const int* row = ei;
    const int* col = ei + E;

    const int nbuck = (N + BS - 1) / BS;          // 391
    const int per   = (E + CHUNKS - 1) / CHUNKS;  // 12500
    const int nb    = (nbuck + 255) / 256;        // 2

    // workspace layout (4B units)
    //  [0, 2E)   : rw2 (node-sorted int2, .x = byte offset)
    //  [2E, 4E)  : rw (bucket-sorted int2), DEAD after nodesort; reused:
    //              xsc half[16N] (8N units) at 2E
    //              tbuf f32[16N] (16N units) at 2E+8N
    //              xs2 half[16N] (8N units) at 2E+24N      (32N <= 2E ok)
    //  [4E, ...) : dis[N], ptr[BS*nbuck+1], part, base, tot, start, bsum
    float*  ws    = (float*)d_ws;
    int2*   rw2   = (int2*)ws;
    int2*   rw    = (int2*)(ws + (size_t)2 * E);
    __half* xsc   = (__half*)(ws + (size_t)2 * E);
    float*  tbuf  = ws + (size_t)2 * E + (size_t)8 * N;
    __half* xs2   = (__half*)(ws + (size_t)2 * E + (size_t)24 * N);
    float*  dis   = ws + (size_t)4 * E;
    int*    ptr   = (int*)(dis + N);
    int*    part  = ptr + (size_t)BS * nbuck + 1;
    int*    base  = part + (size_t)CHUNKS * nbuck;
    int*    tot   = base + (size_t)CHUNKS * nbuck;
    int*    start = tot + nbuck;
    int*    bsum  = start + nbuck + 1;

    hist_kernel<<<CHUNKS, 1024, nbuck * 4, stream>>>(col, part, E, nbuck, per);
    colscan_kernel<<<nbuck, 64, 0, stream>>>(part, base, tot, nbuck);
    scan1_kernel<<<nb, 256, 0, stream>>>(tot, start, bsum, nbuck);
    scan2_kernel<<<1, 512, 0, stream>>>(bsum, nb);
    scan3_kernel<<<(nbuck + 256) / 256 + 1, 256, 0, stream>>>(start, bsum, nbuck, E);
    place_kernel<<<CHUNKS, 1024, 2 * nbuck * 4, stream>>>(row, col, ew, start, base, rw, E, nbuck, per);
    nodesort_kernel<<<nbuck, 512, 0, stream>>>(rw, start, rw2, ptr, dis, N, E, nbuck);

    xsc_kernel<<<(N + 255) / 256, 256, 0, stream>>>(x, dis, xsc, N);
    {
        int gblocks = (N + 15) / 16;   // 16 nodes per 256-thread block
        gather_kernel<0><<<gblocks, 256, 0, stream>>>(ptr, rw2, xsc, dis, b2, tbuf, N);
        mlp_kernel<<<(N + 255) / 256, 256, 0, stream>>>(tbuf, dis, W1, b1, W2, xs2, N);
        gather_kernel<1><<<gblocks, 256, 0, stream>>>(ptr, rw2, xs2, dis, b2, out, N);
    }
}